// Round 8
// baseline (121.584 us; speedup 1.0000x reference)
//
#include <hip/hip_runtime.h>

#define NB 32
#define NN 256
#define DD 64
#define SROW 68          // LDS row stride (floats); b128-friendly, measured ~0 conflicts
#define TPAD 17          // transpose scratch row stride
#define FMAXV 3.402823466e+38f

// R14: single dispatch (window = ~78us fixed + kernel; R13 = 117.5 with
// 39.6us kernel @ 37% VALU-busy on the 32 active CUs). Attack the conv
// loop stalls:
//  - full h row hoisted to 64 VGPRs ONCE per conv (16 ds_read_b128), then
//    the k-loop is PURE s_load+FMA -- no ds/smem lgkmcnt mixing (R13 mixed
//    every 16 k-steps -> lgkmcnt(0) drains serialized the loop).
//  - k-loop fully unrolled, h[k] static (dynamic index -> scratch, rule 20).
//  - weight slice per k loaded as ONE s_load_dwordx16 (ext_vector 16 floats,
//    64B-aligned): 2 loads/k instead of 8 -> 4x fewer drain points.
// VGPR budget: h[64]+ti[16]+tj[16]+temps ~= 110 < 128 cap (1024,4).
// Floor: 13.7us VALU; predict kernel 16-22us, dur ~94-102.

typedef float fv16 __attribute__((ext_vector_type(16)));

__device__ __forceinline__ void conv_reg(
    const float h[DD], int d0, const float* __restrict__ We,
    float ti[16], float tj[16])
{
#pragma unroll
    for (int j = 0; j < 16; ++j) { ti[j] = 0.f; tj[j] = 0.f; }
#pragma unroll
    for (int k = 0; k < DD; ++k) {                       // FULL unroll: static h[k]
        const float hk = h[k];
        fv16 a = *(const fv16*)(We + (size_t)k * DD + d0);        // s_load_dwordx16
        fv16 c = *(const fv16*)(We + (size_t)(DD + k) * DD + d0); // s_load_dwordx16
#pragma unroll
        for (int j = 0; j < 16; ++j) {
            ti[j] = fmaf(hk, a[j], ti[j]);
            tj[j] = fmaf(hk, c[j], tj[j]);
        }
    }
}

__global__ __launch_bounds__(1024, 4) void k_all(
    const float* __restrict__ x,
    const float* __restrict__ W1,  const float* __restrict__ b1,
    const float* __restrict__ g1,  const float* __restrict__ beta1,
    const float* __restrict__ We1, const float* __restrict__ be1,
    const float* __restrict__ ge1, const float* __restrict__ bte1,
    const float* __restrict__ We2, const float* __restrict__ be2,
    const float* __restrict__ ge2, const float* __restrict__ bte2,
    const float* __restrict__ Wg1, const float* __restrict__ bg1,
    const float* __restrict__ Wg2, const float* __restrict__ bg2,
    float* __restrict__ out)
{
    __shared__ __align__(16) float Hs[NN * SROW];   // 69,632 B; also transpose scratch
    __shared__ __align__(16) float PTmax[4][DD], PTmin[4][DD];
    __shared__ __align__(16) float RM[DD], RMn[DD];
    __shared__ __align__(16) float PS[4][DD], PM[4][DD];
    __shared__ __align__(16) float xg[2 * DD];
    __shared__ __align__(16) float hid[DD];

    const int b   = blockIdx.x;
    const int l   = threadIdx.x & 63;                                 // node lane
    const int w   = __builtin_amdgcn_readfirstlane(threadIdx.x >> 6); // wave 0..15
    const int ng  = w >> 2;           // node-group 0..3
    const int d0  = (w & 3) * 16;     // wave-uniform dim slice
    const int n   = ng * 64 + l;      // this thread's node
    const int jd  = l >> 2;           // transpose-read: my dim index (0..15)
    const int cq  = l & 3;            // transpose-read: my node-chunk (0..3)
    float* Ts     = Hs + w * (64 * TPAD);   // per-wave 64x17 scratch

    // ================= P0: layer 1 -> Hs rows =================
    {
        float4 xv = *(const float4*)(x + ((size_t)b * NN + n) * 4);
#pragma unroll
        for (int q = 0; q < 4; ++q) {
            float hq[4];
#pragma unroll
            for (int u = 0; u < 4; ++u) {
                const int d = d0 + 4 * q + u;
                float a = b1[d];
                a = fmaf(xv.x, W1[0 * DD + d], a);
                a = fmaf(xv.y, W1[1 * DD + d], a);
                a = fmaf(xv.z, W1[2 * DD + d], a);
                a = fmaf(xv.w, W1[3 * DD + d], a);
                hq[u] = g1[d] * fmaxf(a, 0.f) + beta1[d];
            }
            *(float4*)(Hs + (size_t)n * SROW + d0 + 4 * q) =
                make_float4(hq[0], hq[1], hq[2], hq[3]);
        }
    }
    __syncthreads();

    float ti[16], tj[16];
    float h[DD];

    // ================= conv1 =================
    // hoist full h row to registers (one DS burst; k-loop is DS-free)
#pragma unroll
    for (int q = 0; q < 16; ++q) {
        float4 hv = *(const float4*)(Hs + (size_t)n * SROW + 4 * q);
        h[4*q+0] = hv.x; h[4*q+1] = hv.y; h[4*q+2] = hv.z; h[4*q+3] = hv.w;
    }
    conv_reg(h, d0, We1, ti, tj);
    __syncthreads();                       // Hs reads done -> scratch reuse ok

    // tj -> transpose scratch
#pragma unroll
    for (int j = 0; j < 16; ++j) Ts[l * TPAD + j] = tj[j];
    __syncthreads();

    // column reduce: 16 in-lane + 4 shuffles
    {
        float mx = -FMAXV, mn = FMAXV;
#pragma unroll
        for (int r = 0; r < 16; ++r) {
            float v = Ts[(cq * 16 + r) * TPAD + jd];
            mx = fmaxf(mx, v); mn = fminf(mn, v);
        }
        mx = fmaxf(mx, __shfl_xor(mx, 1, 64));
        mx = fmaxf(mx, __shfl_xor(mx, 2, 64));
        mn = fminf(mn, __shfl_xor(mn, 1, 64));
        mn = fminf(mn, __shfl_xor(mn, 2, 64));
        if (cq == 0) { PTmax[ng][d0 + jd] = mx; PTmin[ng][d0 + jd] = mn; }
    }
    __syncthreads();

    // combine 4 node-groups
    {
        const int t = threadIdx.x;
        if (t < DD)
            RM[t] = fmaxf(fmaxf(PTmax[0][t], PTmax[1][t]),
                          fmaxf(PTmax[2][t], PTmax[3][t]));
        else if (t < 2 * DD) {
            const int d = t - DD;
            RMn[d] = fminf(fminf(PTmin[0][d], PTmin[1][d]),
                           fminf(PTmin[2][d], PTmin[3][d]));
        }
    }
    __syncthreads();

    // conv1 epilogue -> Hs rows (monotone bn o max)
    {
#pragma unroll
        for (int q = 0; q < 4; ++q) {
            float4 rmx = *(const float4*)(&RM[d0 + 4 * q]);    // broadcast
            float4 rmn = *(const float4*)(&RMn[d0 + 4 * q]);   // broadcast
            const float rmax[4] = {rmx.x, rmx.y, rmx.z, rmx.w};
            const float rmin[4] = {rmn.x, rmn.y, rmn.z, rmn.w};
            float hq[4];
#pragma unroll
            for (int u = 0; u < 4; ++u) {
                const int d = d0 + 4 * q + u;
                const float gv = ge1[d];
                const float sv = ti[4*q+u] + (gv >= 0.f ? rmax[u] : rmin[u]) + be1[d];
                hq[u] = gv * fmaxf(sv, 0.f) + bte1[d];
            }
            *(float4*)(Hs + (size_t)n * SROW + d0 + 4 * q) =
                make_float4(hq[0], hq[1], hq[2], hq[3]);
        }
    }
    __syncthreads();

    // ================= conv2 =================
#pragma unroll
    for (int q = 0; q < 16; ++q) {
        float4 hv = *(const float4*)(Hs + (size_t)n * SROW + 4 * q);
        h[4*q+0] = hv.x; h[4*q+1] = hv.y; h[4*q+2] = hv.z; h[4*q+3] = hv.w;
    }
    conv_reg(h, d0, We2, ti, tj);
    __syncthreads();

#pragma unroll
    for (int j = 0; j < 16; ++j) Ts[l * TPAD + j] = tj[j];
    __syncthreads();

    {
        float mx = -FMAXV, mn = FMAXV;
#pragma unroll
        for (int r = 0; r < 16; ++r) {
            float v = Ts[(cq * 16 + r) * TPAD + jd];
            mx = fmaxf(mx, v); mn = fminf(mn, v);
        }
        mx = fmaxf(mx, __shfl_xor(mx, 1, 64));
        mx = fmaxf(mx, __shfl_xor(mx, 2, 64));
        mn = fminf(mn, __shfl_xor(mn, 1, 64));
        mn = fminf(mn, __shfl_xor(mn, 2, 64));
        if (cq == 0) { PTmax[ng][d0 + jd] = mx; PTmin[ng][d0 + jd] = mn; }
    }
    __syncthreads();

    {
        const int t = threadIdx.x;
        if (t < DD)
            RM[t] = fmaxf(fmaxf(PTmax[0][t], PTmax[1][t]),
                          fmaxf(PTmax[2][t], PTmax[3][t]));
        else if (t < 2 * DD) {
            const int d = t - DD;
            RMn[d] = fminf(fminf(PTmin[0][d], PTmin[1][d]),
                           fminf(PTmin[2][d], PTmin[3][d]));
        }
    }
    __syncthreads();

    // conv2 epilogue -> h3, into transpose scratch for pooling
    {
#pragma unroll
        for (int q = 0; q < 4; ++q) {
            float4 rmx = *(const float4*)(&RM[d0 + 4 * q]);
            float4 rmn = *(const float4*)(&RMn[d0 + 4 * q]);
            const float rmax[4] = {rmx.x, rmx.y, rmx.z, rmx.w};
            const float rmin[4] = {rmn.x, rmn.y, rmn.z, rmn.w};
#pragma unroll
            for (int u = 0; u < 4; ++u) {
                const int d = d0 + 4 * q + u;
                const float gv = ge2[d];
                const float sv = ti[4*q+u] + (gv >= 0.f ? rmax[u] : rmin[u]) + be2[d];
                Ts[l * TPAD + 4 * q + u] = gv * fmaxf(sv, 0.f) + bte2[d];
            }
        }
    }
    __syncthreads();

    // pooling: column reduce sum & max
    {
        float s = 0.f, mx = -FMAXV;
#pragma unroll
        for (int r = 0; r < 16; ++r) {
            float v = Ts[(cq * 16 + r) * TPAD + jd];
            s += v; mx = fmaxf(mx, v);
        }
        s += __shfl_xor(s, 1, 64);
        s += __shfl_xor(s, 2, 64);
        mx = fmaxf(mx, __shfl_xor(mx, 1, 64));
        mx = fmaxf(mx, __shfl_xor(mx, 2, 64));
        if (cq == 0) { PS[ng][d0 + jd] = s; PM[ng][d0 + jd] = mx; }
    }
    __syncthreads();

    // pooling finalize + head MLP
    const int t = threadIdx.x;
    if (t < DD) {
        xg[t] = (PS[0][t] + PS[1][t] + PS[2][t] + PS[3][t]) * (1.f / 256.f);
    } else if (t < 2 * DD) {
        const int d = t - DD;
        xg[t] = fmaxf(fmaxf(PM[0][d], PM[1][d]), fmaxf(PM[2][d], PM[3][d]));
    }
    __syncthreads();
    if (t < DD) {
        float a = bg1[t];
#pragma unroll
        for (int k = 0; k < 2 * DD; ++k) a = fmaf(xg[k], Wg1[k * DD + t], a);
        hid[t] = fmaxf(a, 0.f);
    }
    __syncthreads();
    if (t < 2) {
        float o = bg2[t];
#pragma unroll
        for (int j = 0; j < DD; ++j) o = fmaf(hid[j], Wg2[j * 2 + t], o);
        out[b * 2 + t] = o;
    }
}

extern "C" void kernel_launch(void* const* d_in, const int* in_sizes, int n_in,
                              void* d_out, int out_size, void* d_ws, size_t ws_size,
                              hipStream_t stream) {
    const float* x     = (const float*)d_in[0];
    const float* W1    = (const float*)d_in[1];
    const float* b1    = (const float*)d_in[2];
    const float* g1    = (const float*)d_in[3];
    const float* beta1 = (const float*)d_in[4];
    const float* We1   = (const float*)d_in[5];
    const float* be1   = (const float*)d_in[6];
    const float* ge1   = (const float*)d_in[7];
    const float* bte1  = (const float*)d_in[8];
    const float* We2   = (const float*)d_in[9];
    const float* be2   = (const float*)d_in[10];
    const float* ge2   = (const float*)d_in[11];
    const float* bte2  = (const float*)d_in[12];
    const float* Wg1   = (const float*)d_in[13];
    const float* bg1   = (const float*)d_in[14];
    const float* Wg2   = (const float*)d_in[15];
    const float* bg2   = (const float*)d_in[16];

    k_all<<<dim3(NB), dim3(1024), 0, stream>>>(
        x, W1, b1, g1, beta1,
        We1, be1, ge1, bte1,
        We2, be2, ge2, bte2,
        Wg1, bg1, Wg2, bg2, (float*)d_out);
}

// Round 9
// 120.565 us; speedup vs baseline: 1.0084x; 1.0084x over previous
//
#include <hip/hip_runtime.h>

#define NB 32
#define NN 256
#define DD 64
#define SROW 68          // LDS row stride (floats); b128-friendly, ~0 conflicts measured
#define TPAD 17          // transpose scratch row stride
#define FMAXV 3.402823466e+38f

// R15: R13 structure (best: 117.5 = ~78us fixed window + ~39.6us kernel),
// plus REGISTER PINNING of the h-chunks. R13/R14 post-mortem: compiler
// re-rolled / pass-split the conv loop (VGPR=32/40 vs ~110 intended),
// rematerializing ds_reads of h inside the k-loop -> ds/s_load lgkmcnt
// mixing -> lgkmcnt(0) drains -> 34% VALU efficiency. Empty inline-asm
// "+v" on each h value after the LDS load makes it an opaque VGPR: no
// remat, no re-read; each 16-step k-chunk is then provably DS-free
// (pure s_load+FMA, static indices). Live set ~70 VGPR < 128 cap (1024,4).

__device__ __forceinline__ void conv_full(
    const float* Hs, int n, int d0, const float* __restrict__ We,
    float ti[16], float tj[16])
{
#pragma unroll
    for (int j = 0; j < 16; ++j) { ti[j] = 0.f; tj[j] = 0.f; }
    const float* hrow = Hs + (size_t)n * SROW;
#pragma unroll 1
    for (int kc = 0; kc < 4; ++kc) {           // rolled: I$-sized
        float h[16];
#pragma unroll
        for (int q = 0; q < 4; ++q) {
            float4 hv = *(const float4*)(hrow + kc * 16 + 4 * q);
            h[4*q+0] = hv.x; h[4*q+1] = hv.y; h[4*q+2] = hv.z; h[4*q+3] = hv.w;
        }
        // PIN: h becomes opaque VGPRs -- compiler cannot re-read LDS or fold
#pragma unroll
        for (int q = 0; q < 16; ++q) asm volatile("" : "+v"(h[q]));
#pragma unroll
        for (int kk = 0; kk < 16; ++kk) {      // full unroll: static h[] index
            const float hk = h[kk];
            const float* wi = We + (size_t)(kc * 16 + kk) * DD + d0;        // uniform
            const float* wj = We + (size_t)(DD + kc * 16 + kk) * DD + d0;   // uniform
#pragma unroll
            for (int q = 0; q < 4; ++q) {
                float4 a = *(const float4*)(wi + 4 * q);
                float4 c = *(const float4*)(wj + 4 * q);
                ti[4*q+0] = fmaf(hk, a.x, ti[4*q+0]);
                ti[4*q+1] = fmaf(hk, a.y, ti[4*q+1]);
                ti[4*q+2] = fmaf(hk, a.z, ti[4*q+2]);
                ti[4*q+3] = fmaf(hk, a.w, ti[4*q+3]);
                tj[4*q+0] = fmaf(hk, c.x, tj[4*q+0]);
                tj[4*q+1] = fmaf(hk, c.y, tj[4*q+1]);
                tj[4*q+2] = fmaf(hk, c.z, tj[4*q+2]);
                tj[4*q+3] = fmaf(hk, c.w, tj[4*q+3]);
            }
        }
    }
}

__global__ __launch_bounds__(1024, 4) void k_all(
    const float* __restrict__ x,
    const float* __restrict__ W1,  const float* __restrict__ b1,
    const float* __restrict__ g1,  const float* __restrict__ beta1,
    const float* __restrict__ We1, const float* __restrict__ be1,
    const float* __restrict__ ge1, const float* __restrict__ bte1,
    const float* __restrict__ We2, const float* __restrict__ be2,
    const float* __restrict__ ge2, const float* __restrict__ bte2,
    const float* __restrict__ Wg1, const float* __restrict__ bg1,
    const float* __restrict__ Wg2, const float* __restrict__ bg2,
    float* __restrict__ out)
{
    __shared__ __align__(16) float Hs[NN * SROW];   // 69,632 B; also transpose scratch
    __shared__ __align__(16) float PTmax[4][DD], PTmin[4][DD];
    __shared__ __align__(16) float RM[DD], RMn[DD];
    __shared__ __align__(16) float PS[4][DD], PM[4][DD];
    __shared__ __align__(16) float xg[2 * DD];
    __shared__ __align__(16) float hid[DD];

    const int b   = blockIdx.x;
    const int l   = threadIdx.x & 63;                                 // node lane
    const int w   = __builtin_amdgcn_readfirstlane(threadIdx.x >> 6); // wave 0..15
    const int ng  = w >> 2;           // node-group 0..3
    const int d0  = (w & 3) * 16;     // wave-uniform dim slice
    const int n   = ng * 64 + l;      // this thread's node
    const int jd  = l >> 2;           // transpose-read: my dim index (0..15)
    const int cq  = l & 3;            // transpose-read: my node-chunk (0..3)
    float* Ts     = Hs + w * (64 * TPAD);   // per-wave 64x17 scratch

    // ================= P0: layer 1 -> Hs rows =================
    {
        float4 xv = *(const float4*)(x + ((size_t)b * NN + n) * 4);
#pragma unroll
        for (int q = 0; q < 4; ++q) {
            float hq[4];
#pragma unroll
            for (int u = 0; u < 4; ++u) {
                const int d = d0 + 4 * q + u;
                float a = b1[d];
                a = fmaf(xv.x, W1[0 * DD + d], a);
                a = fmaf(xv.y, W1[1 * DD + d], a);
                a = fmaf(xv.z, W1[2 * DD + d], a);
                a = fmaf(xv.w, W1[3 * DD + d], a);
                hq[u] = g1[d] * fmaxf(a, 0.f) + beta1[d];
            }
            *(float4*)(Hs + (size_t)n * SROW + d0 + 4 * q) =
                make_float4(hq[0], hq[1], hq[2], hq[3]);
        }
    }
    __syncthreads();

    float ti[16], tj[16];

    // ================= conv1 =================
    conv_full(Hs, n, d0, We1, ti, tj);
    __syncthreads();                       // Hs reads done -> scratch reuse ok

    // tj -> transpose scratch
#pragma unroll
    for (int j = 0; j < 16; ++j) Ts[l * TPAD + j] = tj[j];
    __syncthreads();

    // column reduce: 16 in-lane + 4 shuffles
    {
        float mx = -FMAXV, mn = FMAXV;
#pragma unroll
        for (int r = 0; r < 16; ++r) {
            float v = Ts[(cq * 16 + r) * TPAD + jd];
            mx = fmaxf(mx, v); mn = fminf(mn, v);
        }
        mx = fmaxf(mx, __shfl_xor(mx, 1, 64));
        mx = fmaxf(mx, __shfl_xor(mx, 2, 64));
        mn = fminf(mn, __shfl_xor(mn, 1, 64));
        mn = fminf(mn, __shfl_xor(mn, 2, 64));
        if (cq == 0) { PTmax[ng][d0 + jd] = mx; PTmin[ng][d0 + jd] = mn; }
    }
    __syncthreads();

    // combine 4 node-groups
    {
        const int t = threadIdx.x;
        if (t < DD)
            RM[t] = fmaxf(fmaxf(PTmax[0][t], PTmax[1][t]),
                          fmaxf(PTmax[2][t], PTmax[3][t]));
        else if (t < 2 * DD) {
            const int d = t - DD;
            RMn[d] = fminf(fminf(PTmin[0][d], PTmin[1][d]),
                           fminf(PTmin[2][d], PTmin[3][d]));
        }
    }
    __syncthreads();

    // conv1 epilogue -> Hs rows (monotone bn o max)
    {
#pragma unroll
        for (int q = 0; q < 4; ++q) {
            float4 rmx = *(const float4*)(&RM[d0 + 4 * q]);    // broadcast
            float4 rmn = *(const float4*)(&RMn[d0 + 4 * q]);   // broadcast
            const float rmax[4] = {rmx.x, rmx.y, rmx.z, rmx.w};
            const float rmin[4] = {rmn.x, rmn.y, rmn.z, rmn.w};
            float hq[4];
#pragma unroll
            for (int u = 0; u < 4; ++u) {
                const int d = d0 + 4 * q + u;
                const float gv = ge1[d];
                const float sv = ti[4*q+u] + (gv >= 0.f ? rmax[u] : rmin[u]) + be1[d];
                hq[u] = gv * fmaxf(sv, 0.f) + bte1[d];
            }
            *(float4*)(Hs + (size_t)n * SROW + d0 + 4 * q) =
                make_float4(hq[0], hq[1], hq[2], hq[3]);
        }
    }
    __syncthreads();

    // ================= conv2 =================
    conv_full(Hs, n, d0, We2, ti, tj);
    __syncthreads();

#pragma unroll
    for (int j = 0; j < 16; ++j) Ts[l * TPAD + j] = tj[j];
    __syncthreads();

    {
        float mx = -FMAXV, mn = FMAXV;
#pragma unroll
        for (int r = 0; r < 16; ++r) {
            float v = Ts[(cq * 16 + r) * TPAD + jd];
            mx = fmaxf(mx, v); mn = fminf(mn, v);
        }
        mx = fmaxf(mx, __shfl_xor(mx, 1, 64));
        mx = fmaxf(mx, __shfl_xor(mx, 2, 64));
        mn = fminf(mn, __shfl_xor(mn, 1, 64));
        mn = fminf(mn, __shfl_xor(mn, 2, 64));
        if (cq == 0) { PTmax[ng][d0 + jd] = mx; PTmin[ng][d0 + jd] = mn; }
    }
    __syncthreads();

    {
        const int t = threadIdx.x;
        if (t < DD)
            RM[t] = fmaxf(fmaxf(PTmax[0][t], PTmax[1][t]),
                          fmaxf(PTmax[2][t], PTmax[3][t]));
        else if (t < 2 * DD) {
            const int d = t - DD;
            RMn[d] = fminf(fminf(PTmin[0][d], PTmin[1][d]),
                           fminf(PTmin[2][d], PTmin[3][d]));
        }
    }
    __syncthreads();

    // conv2 epilogue -> h3, into transpose scratch for pooling
    {
#pragma unroll
        for (int q = 0; q < 4; ++q) {
            float4 rmx = *(const float4*)(&RM[d0 + 4 * q]);
            float4 rmn = *(const float4*)(&RMn[d0 + 4 * q]);
            const float rmax[4] = {rmx.x, rmx.y, rmx.z, rmx.w};
            const float rmin[4] = {rmn.x, rmn.y, rmn.z, rmn.w};
#pragma unroll
            for (int u = 0; u < 4; ++u) {
                const int d = d0 + 4 * q + u;
                const float gv = ge2[d];
                const float sv = ti[4*q+u] + (gv >= 0.f ? rmax[u] : rmin[u]) + be2[d];
                Ts[l * TPAD + 4 * q + u] = gv * fmaxf(sv, 0.f) + bte2[d];
            }
        }
    }
    __syncthreads();

    // pooling: column reduce sum & max
    {
        float s = 0.f, mx = -FMAXV;
#pragma unroll
        for (int r = 0; r < 16; ++r) {
            float v = Ts[(cq * 16 + r) * TPAD + jd];
            s += v; mx = fmaxf(mx, v);
        }
        s += __shfl_xor(s, 1, 64);
        s += __shfl_xor(s, 2, 64);
        mx = fmaxf(mx, __shfl_xor(mx, 1, 64));
        mx = fmaxf(mx, __shfl_xor(mx, 2, 64));
        if (cq == 0) { PS[ng][d0 + jd] = s; PM[ng][d0 + jd] = mx; }
    }
    __syncthreads();

    // pooling finalize + head MLP
    const int t = threadIdx.x;
    if (t < DD) {
        xg[t] = (PS[0][t] + PS[1][t] + PS[2][t] + PS[3][t]) * (1.f / 256.f);
    } else if (t < 2 * DD) {
        const int d = t - DD;
        xg[t] = fmaxf(fmaxf(PM[0][d], PM[1][d]), fmaxf(PM[2][d], PM[3][d]));
    }
    __syncthreads();
    if (t < DD) {
        float a = bg1[t];
#pragma unroll
        for (int k = 0; k < 2 * DD; ++k) a = fmaf(xg[k], Wg1[k * DD + t], a);
        hid[t] = fmaxf(a, 0.f);
    }
    __syncthreads();
    if (t < 2) {
        float o = bg2[t];
#pragma unroll
        for (int j = 0; j < DD; ++j) o = fmaf(hid[j], Wg2[j * 2 + t], o);
        out[b * 2 + t] = o;
    }
}

extern "C" void kernel_launch(void* const* d_in, const int* in_sizes, int n_in,
                              void* d_out, int out_size, void* d_ws, size_t ws_size,
                              hipStream_t stream) {
    const float* x     = (const float*)d_in[0];
    const float* W1    = (const float*)d_in[1];
    const float* b1    = (const float*)d_in[2];
    const float* g1    = (const float*)d_in[3];
    const float* beta1 = (const float*)d_in[4];
    const float* We1   = (const float*)d_in[5];
    const float* be1   = (const float*)d_in[6];
    const float* ge1   = (const float*)d_in[7];
    const float* bte1  = (const float*)d_in[8];
    const float* We2   = (const float*)d_in[9];
    const float* be2   = (const float*)d_in[10];
    const float* ge2   = (const float*)d_in[11];
    const float* bte2  = (const float*)d_in[12];
    const float* Wg1   = (const float*)d_in[13];
    const float* bg1   = (const float*)d_in[14];
    const float* Wg2   = (const float*)d_in[15];
    const float* bg2   = (const float*)d_in[16];

    k_all<<<dim3(NB), dim3(1024), 0, stream>>>(
        x, W1, b1, g1, beta1,
        We1, be1, ge1, bte1,
        We2, be2, ge2, bte2,
        Wg1, bg1, Wg2, bg2, (float*)d_out);
}